// Round 11
// baseline (152.115 us; speedup 1.0000x reference)
//
#include <hip/hip_runtime.h>
#include <hip/hip_bf16.h>

// B=4, T=2048, C=1024, H=16, D=64. fp32 in/out.
// cast_x / transpose weights -> qkv_gemm (256x128, wave 128x64, 32x32x16 MFMA, 2-deep
// counted-vmcnt) -> tv -> attn (unchanged) -> out_gemm (same core + bias).

#define B_ 4
#define T_ 2048
#define C_ 1024
#define H_ 16
#define D_ 64
#define M_ (B_*T_)      // 8192

typedef unsigned short u16;
typedef unsigned short ushort8 __attribute__((ext_vector_type(8)));
typedef unsigned int uint4v __attribute__((ext_vector_type(4)));
typedef int int2v __attribute__((ext_vector_type(2)));
typedef __attribute__((ext_vector_type(8))) short bf16x8;
typedef __attribute__((ext_vector_type(16))) float f32x16;

__device__ __forceinline__ u16 f2bf(float f) {
    __hip_bfloat16 h = __float2bfloat16(f);
    return *reinterpret_cast<u16*>(&h);
}
__device__ __forceinline__ unsigned pkt(float lo, float hi2) {
    return __builtin_amdgcn_perm(__float_as_uint(hi2), __float_as_uint(lo), 0x07060302u);
}
__device__ __forceinline__ void gload_lds16(const void* g, void* lds) {
    __builtin_amdgcn_global_load_lds((const __attribute__((address_space(1))) unsigned int*)g,
                                     (__attribute__((address_space(3))) unsigned int*)lds, 16, 0, 0);
}
__device__ __forceinline__ int swz4(int r) { return (r ^ (r >> 2)) & 3; }   // 64B-row granule swizzle

// ---------------- cast x -> bf16 ----------------
__global__ __launch_bounds__(256) void cast_x(const float* __restrict__ in, u16* __restrict__ out) {
    int i = (blockIdx.x * 256 + threadIdx.x) * 8;
    float4 a = *reinterpret_cast<const float4*>(in + i);
    float4 b = *reinterpret_cast<const float4*>(in + i + 4);
    ushort8 o;
    o[0]=f2bf(a.x); o[1]=f2bf(a.y); o[2]=f2bf(a.z); o[3]=f2bf(a.w);
    o[4]=f2bf(b.x); o[5]=f2bf(b.y); o[6]=f2bf(b.z); o[7]=f2bf(b.w);
    *reinterpret_cast<ushort8*>(out + i) = o;
}

// ---------------- 64x64 transpose+cast ----------------
__device__ __forceinline__ void ttile64(const float* __restrict__ in, int ldin,
                                        u16* __restrict__ out, int ldout, float scale) {
    __shared__ float t[64][65];
    const int tid = threadIdx.x;
    {
        int c = tid & 63, rr = tid >> 6;
        #pragma unroll
        for (int i = 0; i < 16; ++i) {
            int r = i * 4 + rr;
            t[r][c] = in[(size_t)r * ldin + c];
        }
    }
    __syncthreads();
    {
        int r2 = tid & 63, cg = tid >> 6;
        #pragma unroll
        for (int i = 0; i < 16; ++i) {
            int cc = i * 4 + cg;
            out[(size_t)cc * ldout + r2] = f2bf(t[r2][cc] * scale);
        }
    }
}

__global__ __launch_bounds__(256) void tw_qkv(const float* __restrict__ Wq, const float* __restrict__ Wk,
                                              const float* __restrict__ Wv, u16* __restrict__ Wt) {
    const int z = blockIdx.y;
    const int which = z >> 4, h = z & 15;
    const float* W = (which == 0 ? Wq : which == 1 ? Wk : Wv) + (size_t)h * C_ * D_;
    const int r0 = blockIdx.x * 64;
    const float scale = (which == 0) ? 0.03125f * 1.4426950408889634f : 1.f;  // C^-0.5 * log2(e)
    ttile64(W + (size_t)r0 * D_, D_, Wt + (size_t)(which * 16 + h) * 64 * C_ + r0, C_, scale);
}

__global__ __launch_bounds__(256) void tw_p(const float* __restrict__ Wp, u16* __restrict__ Wpt) {
    const int r0 = blockIdx.x * 64, c0 = blockIdx.y * 64;
    ttile64(Wp + (size_t)r0 * C_ + c0, C_, Wpt + (size_t)c0 * C_ + r0, C_, 1.f);
}

// ---------------- V [b,h,t,d] -> V^T [b,h,d,t] ----------------
__global__ __launch_bounds__(256) void tv(const u16* __restrict__ v, u16* __restrict__ vT) {
    __shared__ u16 t[64][72];
    const int tid = threadIdx.x;
    const int t0 = blockIdx.x * 64, bh = blockIdx.y;
    const u16* src = v + ((size_t)bh * T_ + t0) * D_;
    #pragma unroll
    for (int it = 0; it < 2; ++it) {
        int idx = it * 256 + tid;
        int r = idx >> 3, c8 = (idx & 7) * 8;
        *reinterpret_cast<ushort8*>(&t[r][c8]) =
            *reinterpret_cast<const ushort8*>(src + (size_t)r * D_ + c8);
    }
    __syncthreads();
    #pragma unroll
    for (int it = 0; it < 2; ++it) {
        int idx = it * 256 + tid;
        int d = idx >> 3, c8 = (idx & 7) * 8;
        ushort8 w;
        #pragma unroll
        for (int i = 0; i < 8; ++i) w[i] = t[c8 + i][d];
        *reinterpret_cast<ushort8*>(vT + ((size_t)bh * D_ + d) * T_ + t0 + c8) = w;
    }
}

// ---------------- GEMM core v3: BM=256 BN=128 BK=32, 4 waves (2Mx2N), wave tile 128x64 ----------------
// 32x32x16 MFMA (faster pipe, fewer instr). 2-deep dbuf 48KB -> 2 blocks/CU. Uniform 6 gloads/thread
// per K-tile -> exact per-wave vmcnt counts (steady 6, tail 0). Raw s_barrier + sched_barrier fences.
__device__ __forceinline__ void gemm_core3(const u16* __restrict__ A, const u16* __restrict__ Bt,
                                           int m0, int n0, u16* lds, f32x16 (&acc)[4][2]) {
    const int tid = threadIdx.x;            // 256
    const int wid = tid >> 6, lane = tid & 63;
    const int l31 = lane & 31, hi = lane >> 5;
    const int wr = wid >> 1, wc = wid & 1;

    // staging sources: slots 0..1023 = A (256 rows x 4 granules), 1024..1535 = B (128 rows x 4)
    const u16* src[6];
    #pragma unroll
    for (int it = 0; it < 6; ++it) {
        int slot = it * 256 + tid;
        int row, g;
        const u16* base;
        if (it < 4) { row = slot >> 2; g = slot & 3; base = A + (size_t)(m0 + row) * C_; }
        else        { int s2 = slot - 1024; row = s2 >> 2; g = s2 & 3; base = Bt + (size_t)(n0 + row) * C_; }
        src[it] = base + ((g ^ swz4(row)) * 8);
    }

    // fragment byte-offsets within one buf (A at 0, B at 16384)
    const char* lb = reinterpret_cast<const char*>(lds);
    int aoff[2][4], boff[2][2];
    #pragma unroll
    for (int kk = 0; kk < 2; ++kk) {
        #pragma unroll
        for (int mt = 0; mt < 4; ++mt) {
            int row = wr * 128 + mt * 32 + l31;
            aoff[kk][mt] = row * 64 + (((kk * 2 + hi) ^ swz4(row)) & 3) * 16;
        }
        #pragma unroll
        for (int nt = 0; nt < 2; ++nt) {
            int row = wc * 64 + nt * 32 + l31;
            boff[kk][nt] = 16384 + row * 64 + (((kk * 2 + hi) ^ swz4(row)) & 3) * 16;
        }
    }

#define STG(BU16)                                                                   \
    {                                                                               \
        _Pragma("unroll")                                                           \
        for (int it = 0; it < 6; ++it) {                                            \
            gload_lds16(src[it], lds + (BU16) + (it * 256 + tid) * 8);              \
            src[it] += 32;                                                          \
        }                                                                           \
    }

    STG(0);          // K-tile 0 -> buf 0
    STG(12288);      // K-tile 1 -> buf 1

    #pragma unroll
    for (int t = 0; t < 32; ++t) {
        if (t < 31) { asm volatile("s_waitcnt vmcnt(6)" ::: "memory"); }
        else        { asm volatile("s_waitcnt vmcnt(0)" ::: "memory"); }
        __builtin_amdgcn_sched_barrier(0);
        __builtin_amdgcn_s_barrier();
        __builtin_amdgcn_sched_barrier(0);

        const char* lbuf = lb + (t & 1) * 24576;
        __builtin_amdgcn_s_setprio(1);
        #pragma unroll
        for (int kk = 0; kk < 2; ++kk) {
            bf16x8 bf0 = *reinterpret_cast<const bf16x8*>(lbuf + boff[kk][0]);
            bf16x8 bf1 = *reinterpret_cast<const bf16x8*>(lbuf + boff[kk][1]);
            #pragma unroll
            for (int mt = 0; mt < 4; ++mt) {
                bf16x8 af = *reinterpret_cast<const bf16x8*>(lbuf + aoff[kk][mt]);
                acc[mt][0] = __builtin_amdgcn_mfma_f32_32x32x16_bf16(af, bf0, acc[mt][0], 0, 0, 0);
                acc[mt][1] = __builtin_amdgcn_mfma_f32_32x32x16_bf16(af, bf1, acc[mt][1], 0, 0, 0);
            }
        }
        __builtin_amdgcn_s_setprio(0);
        __builtin_amdgcn_sched_barrier(0);
        __builtin_amdgcn_s_barrier();
        __builtin_amdgcn_sched_barrier(0);
        if (t + 2 < 32) STG((t & 1) * 12288);
    }
#undef STG
}

// ---------------- QKV GEMM: [8192x1024]@[1024x3072] -> q/k/v bf16 [B,H,T,D] ----------------
__global__ __launch_bounds__(256, 2) void qkv_gemm(const u16* __restrict__ xb, const u16* __restrict__ Wt,
                                                   u16* __restrict__ q, u16* __restrict__ k,
                                                   u16* __restrict__ v) {
    __shared__ u16 lds[2 * 12288];     // 48 KiB -> 2 blocks/CU
    f32x16 acc[4][2];
    #pragma unroll
    for (int i = 0; i < 4; ++i)
        #pragma unroll
        for (int j = 0; j < 2; ++j)
            #pragma unroll
            for (int r = 0; r < 16; ++r) acc[i][j][r] = 0.f;
    const int m0 = blockIdx.x * 256, n0 = blockIdx.y * 128;
    gemm_core3(xb, Wt, m0, n0, lds, acc);

    const int tid = threadIdx.x, wid = tid >> 6, lane = tid & 63;
    const int l31 = lane & 31, hi = lane >> 5;
    const int wr = wid >> 1, wc = wid & 1;
    #pragma unroll
    for (int mt = 0; mt < 4; ++mt) {
        #pragma unroll
        for (int nt = 0; nt < 2; ++nt) {
            int n = n0 + wc * 64 + nt * 32 + l31;
            int which = n >> 10, h = (n >> 6) & 15, d = n & 63;
            u16* dst = (which == 0 ? q : which == 1 ? k : v);
            #pragma unroll
            for (int r = 0; r < 16; ++r) {
                int m = m0 + wr * 128 + mt * 32 + (r & 3) + 8 * (r >> 2) + 4 * hi;
                int b = m >> 11, t = m & (T_ - 1);
                dst[((size_t)(b * H_ + h) * T_ + t) * D_ + d] = f2bf(acc[mt][nt][r]);
            }
        }
    }
}

// ---------------- Output GEMM: [8192x1024]@[1024x1024] + bias -> fp32 ----------------
__global__ __launch_bounds__(256, 2) void out_gemm(const u16* __restrict__ ob, const u16* __restrict__ Wpt,
                                                   const float* __restrict__ bp, float* __restrict__ out) {
    __shared__ u16 lds[2 * 12288];
    f32x16 acc[4][2];
    #pragma unroll
    for (int i = 0; i < 4; ++i)
        #pragma unroll
        for (int j = 0; j < 2; ++j)
            #pragma unroll
            for (int r = 0; r < 16; ++r) acc[i][j][r] = 0.f;
    const int m0 = blockIdx.x * 256, n0 = blockIdx.y * 128;
    gemm_core3(ob, Wpt, m0, n0, lds, acc);

    const int tid = threadIdx.x, wid = tid >> 6, lane = tid & 63;
    const int l31 = lane & 31, hi = lane >> 5;
    const int wr = wid >> 1, wc = wid & 1;
    #pragma unroll
    for (int mt = 0; mt < 4; ++mt) {
        #pragma unroll
        for (int nt = 0; nt < 2; ++nt) {
            int n = n0 + wc * 64 + nt * 32 + l31;
            float bv = bp[n];
            #pragma unroll
            for (int r = 0; r < 16; ++r) {
                int m = m0 + wr * 128 + mt * 32 + (r & 3) + 8 * (r >> 2) + 4 * hi;
                out[(size_t)m * C_ + n] = acc[mt][nt][r] + bv;
            }
        }
    }
}

// ---------------- attn compute tile (unchanged from round 10) ----------------
template<int CUR>
__device__ __forceinline__ void attn_tile(const char* const (&pf)[4], const bf16x8 (&qf)[4],
                                          const f32x16& z16, float& lrun,
                                          f32x16& oacc0, f32x16& oacc1,
                                          bool isdiag, int relq, int hi) {
    f32x16 st0, st1;
    __builtin_amdgcn_s_setprio(1);
    {
        bf16x8 ka0 = *reinterpret_cast<const bf16x8*>(pf[0] + CUR * 32768);
        bf16x8 ka1 = *reinterpret_cast<const bf16x8*>(pf[0] + CUR * 32768 + 4096);
        st0 = __builtin_amdgcn_mfma_f32_32x32x16_bf16(ka0, qf[0], z16, 0, 0, 0);
        st1 = __builtin_amdgcn_mfma_f32_32x32x16_bf16(ka1, qf[0], z16, 0, 0, 0);
    }
    #pragma unroll
    for (int kc = 1; kc < 4; ++kc) {
        bf16x8 ka0 = *reinterpret_cast<const bf16x8*>(pf[kc] + CUR * 32768);
        bf16x8 ka1 = *reinterpret_cast<const bf16x8*>(pf[kc] + CUR * 32768 + 4096);
        st0 = __builtin_amdgcn_mfma_f32_32x32x16_bf16(ka0, qf[kc], st0, 0, 0, 0);
        st1 = __builtin_amdgcn_mfma_f32_32x32x16_bf16(ka1, qf[kc], st1, 0, 0, 0);
    }
    __builtin_amdgcn_s_setprio(0);

    if (isdiag) {
        #pragma unroll
        for (int rr = 0; rr < 16; ++rr) {
            int sl = (rr & 3) + 8 * (rr >> 2) + 4 * hi;
            if (sl > relq)      st0[rr] = -INFINITY;
            if (sl + 32 > relq) st1[rr] = -INFINITY;
        }
    }

    float rsum = 0.f;
    #pragma unroll
    for (int rr = 0; rr < 16; ++rr) {
        st0[rr] = __builtin_amdgcn_exp2f(st0[rr]);
        st1[rr] = __builtin_amdgcn_exp2f(st1[rr]);
        rsum += st0[rr] + st1[rr];
    }
    rsum += __shfl_xor(rsum, 32);
    lrun += rsum;

    bf16x8 pa0, pa1, pa2, pa3;
#if __has_builtin(__builtin_amdgcn_permlane32_swap)
#define MK_PA(PA, SV, RB)                                                          \
    {                                                                              \
        int X0 = (int)pkt(SV[RB + 0], SV[RB + 1]);                                 \
        int X1 = (int)pkt(SV[RB + 2], SV[RB + 3]);                                 \
        int Y0 = (int)pkt(SV[RB + 4], SV[RB + 5]);                                 \
        int Y1 = (int)pkt(SV[RB + 6], SV[RB + 7]);                                 \
        int2v r0 = __builtin_amdgcn_permlane32_swap(X0, Y0, false, false);         \
        int2v r1 = __builtin_amdgcn_permlane32_swap(X1, Y1, false, false);         \
        uint4v w; w[0] = (unsigned)r0[0]; w[1] = (unsigned)r1[0];                  \
        w[2] = (unsigned)r0[1]; w[3] = (unsigned)r1[1];                            \
        PA = __builtin_bit_cast(bf16x8, w);                                        \
    }
#else
#define MK_PA(PA, SV, RB)                                                          \
    {                                                                              \
        unsigned X0 = pkt(SV[RB + 0], SV[RB + 1]);                                 \
        unsigned X1 = pkt(SV[RB + 2], SV[RB + 3]);                                 \
        unsigned Y0 = pkt(SV[RB + 4], SV[RB + 5]);                                 \
        unsigned sX0 = __shfl_xor(X0, 32), sY0 = __shfl_xor(Y0, 32);               \
        unsigned Y1 = pkt(SV[RB + 6], SV[RB + 7]);                                 \
        unsigned sX1 = __shfl_xor(X1, 32), sY1 = __shfl_xor(Y1, 32);               \
        uint4v w;                                                                  \
        w[0] = hi ? sY0 : X0; w[1] = hi ? sY1 : X1;                                \
        w[2] = hi ? Y0 : sX0; w[3] = hi ? Y1 : sX1;                                \
        PA = __builtin_bit_cast(bf16x8, w);                                        \
    }
#endif
    MK_PA(pa0, st0, 0); MK_PA(pa1, st0, 8); MK_PA(pa2, st1, 0); MK_PA(pa3, st1, 8);
#undef MK_PA

    __builtin_amdgcn_s_setprio(1);
#define PV_STEP(SCJ, PAV)                                                          \
    {                                                                              \
        bf16x8 va0 = *reinterpret_cast<const bf16x8*>(pf[SCJ] + CUR * 32768 + 16384);        \
        bf16x8 va1 = *reinterpret_cast<const bf16x8*>(pf[SCJ] + CUR * 32768 + 16384 + 4096); \
        oacc0 = __builtin_amdgcn_mfma_f32_32x32x16_bf16(va0, PAV, oacc0, 0, 0, 0); \
        oacc1 = __builtin_amdgcn_mfma_f32_32x32x16_bf16(va1, PAV, oacc1, 0, 0, 0); \
    }
    PV_STEP(0, pa0) PV_STEP(1, pa1) PV_STEP(2, pa2) PV_STEP(3, pa3)
#undef PV_STEP
    __builtin_amdgcn_s_setprio(0);
}

// ---------------- MFMA flash attention (unchanged from round 10) ----------------
__global__ __launch_bounds__(512, 4) void attn_mfma(const u16* __restrict__ q,
                                                    const u16* __restrict__ k,
                                                    const u16* __restrict__ vT,
                                                    u16* __restrict__ o) {
    __shared__ u16 smem[32768];

    const int tid  = threadIdx.x;
    const int wid  = tid >> 6;
    const int lane = tid & 63;
    const int l31  = lane & 31;
    const int hi   = lane >> 5;

    const int lin = blockIdx.x;
    const int r   = lin & 255;
    const int f   = lin >> 8;
    const int bh  = r & 63;
    const int e   = r >> 6;
    const int qb  = f ? (7 - e) : e;

    const int q0 = qb * 256;
    const size_t base = (size_t)bh * T_ * D_;
    const u16* kp  = k  + base;
    const u16* vtp = vT + (size_t)bh * D_ * T_;
    const int qglob = q0 + wid * 32 + l31;

    bf16x8 qf[4];
    {
        const u16* qp = q + base + (size_t)qglob * D_;
        #pragma unroll
        for (int kc = 0; kc < 4; ++kc)
            qf[kc] = *reinterpret_cast<const bf16x8*>(qp + kc * 16 + hi * 8);
    }

    const int rw = tid >> 3;
    const int cg = (tid & 7) ^ (rw & 7);
    const u16* gK = kp  + (size_t)rw * D_ + cg * 8;
    const u16* gV = vtp + (size_t)rw * T_ + cg * 8;

    u16* sbase = &smem[0];
    u16* dK = sbase + tid * 8;
    u16* dV = sbase + 8192 + tid * 8;

    const char* pf[4];
    #pragma unroll
    for (int j = 0; j < 4; ++j)
        pf[j] = reinterpret_cast<const char*>(sbase) + l31 * 128 + (((j * 2 + hi) ^ (l31 & 7)) << 4);

    float lrun = 0.f;
    f32x16 oacc0, oacc1, z16;
    #pragma unroll
    for (int rr = 0; rr < 16; ++rr) { oacc0[rr] = 0.f; oacc1[rr] = 0.f; z16[rr] = 0.f; }

    const int ntile  = 4 * qb + 4;
    const int diag_t = 4 * qb + (wid >> 1);
    const int relq   = 32 * (wid & 1) + l31;

#define STG(BUFU16)                                                                \
    {                                                                              \
        gload_lds16(gK, dK + (BUFU16)); gload_lds16(gV, dV + (BUFU16));            \
        gK += 64 * D_; gV += 64;                                                   \
    }

    STG(0);
    __syncthreads();

    for (int tt = 0; tt < ntile; tt += 2) {
        if (tt + 1 < ntile) STG(16384);
        if (tt <= diag_t)
            attn_tile<0>(pf, qf, z16, lrun, oacc0, oacc1, tt == diag_t, relq, hi);
        __syncthreads();
        if (tt + 2 < ntile) STG(0);
        if (tt + 1 <= diag_t)
            attn_tile<1>(pf, qf, z16, lrun, oacc0, oacc1, tt + 1 == diag_t, relq, hi);
        __syncthreads();
    }
#undef STG

    float linv = 1.f / lrun;
    float* ot = reinterpret_cast<float*>(sbase) + wid * 2048;
    #pragma unroll
    for (int rr = 0; rr < 16; ++rr) {
        int d0v = (rr & 3) + 8 * (rr >> 2) + 4 * hi;
        int d1v = d0v + 32;
        ot[l31 * 64 + (((d0v >> 2) ^ (l31 & 7)) << 2) + (d0v & 3)] = oacc0[rr] * linv;
        ot[l31 * 64 + (((d1v >> 2) ^ (l31 & 7)) << 2) + (d1v & 3)] = oacc1[rr] * linv;
    }

    const int b = bh >> 4, h = bh & 15;
    const int qrow = lane >> 1;
    const int d0 = (lane & 1) * 32;
    u16 tmp[32];
    #pragma unroll
    for (int i = 0; i < 8; ++i) {
        int g = ((d0 >> 2) + i) ^ (qrow & 7);
        float4 fv = *reinterpret_cast<const float4*>(&ot[qrow * 64 + (g << 2)]);
        tmp[i * 4 + 0] = f2bf(fv.x); tmp[i * 4 + 1] = f2bf(fv.y);
        tmp[i * 4 + 2] = f2bf(fv.z); tmp[i * 4 + 3] = f2bf(fv.w);
    }
    u16* orow = o + ((size_t)b * T_ + q0 + wid * 32 + qrow) * C_ + h * 64 + d0;
    #pragma unroll
    for (int j = 0; j < 4; ++j)
        *reinterpret_cast<ushort8*>(orow + j * 8) = *reinterpret_cast<ushort8*>(&tmp[j * 8]);
}

extern "C" void kernel_launch(void* const* d_in, const int* in_sizes, int n_in,
                              void* d_out, int out_size, void* d_ws, size_t ws_size,
                              hipStream_t stream) {
    const float* x  = (const float*)d_in[0];
    const float* Wq = (const float*)d_in[1];
    const float* Wk = (const float*)d_in[2];
    const float* Wv = (const float*)d_in[3];
    const float* Wp = (const float*)d_in[4];
    const float* bp = (const float*)d_in[5];
    float* out = (float*)d_out;

    const size_t E = (size_t)M_ * C_;
    u16* xb  = (u16*)d_ws;                   // reused as vT after qkv_gemm
    u16* qb  = xb  + E;
    u16* kb  = qb  + E;
    u16* vb  = kb  + E;
    u16* obf = vb  + E;
    u16* Wt  = obf + E;                      // [3072][1024]
    u16* Wpt = Wt  + (size_t)3072 * 1024;    // [1024][1024]
    u16* vTb = xb;                           // alias: xb dead after qkv_gemm

    cast_x<<<(E / 2048), 256, 0, stream>>>(x, xb);
    tw_qkv<<<dim3(16, 48), 256, 0, stream>>>(Wq, Wk, Wv, Wt);
    tw_p<<<dim3(16, 16), 256, 0, stream>>>(Wp, Wpt);

    qkv_gemm<<<dim3(M_ / 256, 3072 / 128), 256, 0, stream>>>(xb, Wt, qb, kb, vb);

    tv<<<dim3(T_ / 64, B_ * H_), 256, 0, stream>>>(vb, vTb);

    attn_mfma<<<dim3(512), 512, 0, stream>>>(qb, kb, vTb, obf);

    out_gemm<<<dim3(M_ / 256, C_ / 128), 256, 0, stream>>>(obf, Wpt, bp, out);
}